// Round 18
// baseline (605.816 us; speedup 1.0000x reference)
//
#include <hip/hip_runtime.h>
#include <math.h>

#define Bb 32
#define Pp 1024
#define Nn 1024

typedef unsigned short u16;
typedef __bf16 bf16x8 __attribute__((ext_vector_type(8)));
typedef float f32x4 __attribute__((ext_vector_type(4)));
typedef u16 us8 __attribute__((ext_vector_type(8)));
typedef u16 us4 __attribute__((ext_vector_type(4)));

#define MFMA __builtin_amdgcn_mfma_f32_16x16x32_bf16

static constexpr float INV_SQRT_E = 0.08838834764831845f;  // 1/sqrt(128)

__device__ __forceinline__ bf16x8 asbf(us8 v) { return __builtin_bit_cast(bf16x8, v); }

// RTN split: x ~= hi + lo to ~2^-17 rel
__device__ __forceinline__ void bsplit(float x, u16& h, u16& l) {
  unsigned u = __float_as_uint(x);
  unsigned r = u + 0x7FFF + ((u >> 16) & 1);
  h = (u16)(r >> 16);
  float hf = __uint_as_float((unsigned)h << 16);
  float lof = x - hf;
  unsigned u2 = __float_as_uint(lof);
  unsigned r2 = u2 + 0x7FFF + ((u2 >> 16) & 1);
  l = (u16)(r2 >> 16);
}

// trunc split: x ~= hi + lo to ~2^-16 rel, cheap
__device__ __forceinline__ void tsplit(float x, u16& h, u16& l) {
  unsigned u = __float_as_uint(x);
  h = (u16)(u >> 16);
  float lof = x - __uint_as_float(u & 0xFFFF0000u);
  l = (u16)(__float_as_uint(lof) >> 16);
}

// exp(10*tanh(s)) with rcp instead of full divide (~1e-7 rel err)
__device__ __forceinline__ float exp10tanh(float s) {
  float ax = fabsf(s);
  float u = __expf(-2.0f * ax);                    // (0,1]
  float r = __builtin_amdgcn_rcpf(1.0f + u);
  float tt = fmaf(-2.0f * u, r, 1.0f);             // tanh(ax)
  tt = copysignf(tt, s);
  return __expf(10.0f * tt);
}

// ---------------- K0: transposed split weight planes ----------------
__global__ __launch_bounds__(256) void prep_weights(
    const float* __restrict__ Wq1, const float* __restrict__ Wq2,
    const float* __restrict__ Wql, const float* __restrict__ Wk,
    const float* __restrict__ Wv, u16* __restrict__ wcat_hi, u16* __restrict__ wcat_lo,
    u16* __restrict__ wkv_hi, u16* __restrict__ wkv_lo) {
  int t = threadIdx.x;
  if (blockIdx.x == 0) {
    for (int i = t; i < 128 * 384; i += 256) {
      int c = i / 384, k = i % 384;
      float v = (k < 128) ? Wq1[k * 128 + c]
                          : (k < 256) ? Wq2[(k - 128) * 128 + c] : Wql[(k - 256) * 128 + c];
      u16 h, l;
      bsplit(v, h, l);
      wcat_hi[i] = h;
      wcat_lo[i] = l;
    }
  } else {
    for (int i = t; i < 256 * 128; i += 256) {
      int c = i >> 7, k = i & 127;
      float v = (c < 128) ? Wk[k * 128 + c] : Wv[k * 128 + (c - 128)];
      u16 h, l;
      bsplit(v, h, l);
      wkv_hi[i] = h;
      wkv_lo[i] = l;
    }
  }
}

// ---------------- K1: k/v GEMM -> ekkP ([b][nch128][c256][8]) + nodesP ----------------
__global__ __launch_bounds__(256, 1) void kv_prep(
    const float* __restrict__ nodes, const u16* __restrict__ wkv_hi,
    const u16* __restrict__ wkv_lo, u16* __restrict__ ekkP_hi, u16* __restrict__ ekkP_lo,
    u16* __restrict__ nodesP_hi, u16* __restrict__ nodesP_lo) {
  __shared__ u16 a_hi[32 * 136], a_lo[32 * 136];
  __shared__ float kvbuf[32 * 264];
  const int t = threadIdx.x;
  const int xcd = blockIdx.x & 7, jj = blockIdx.x >> 3;
  const int b = xcd * 4 + (jj >> 5);
  const int n0 = (jj & 31) * 32;
  for (int i = t; i < 4096; i += 256) {
    int n = i >> 7, d = i & 127;
    float v = nodes[((long)(b * 1024 + n0 + n)) * 128 + d];
    u16 h, l;
    bsplit(v, h, l);
    a_hi[n * 136 + d] = h;
    a_lo[n * 136 + d] = l;
  }
  __syncthreads();
  const int lane = t & 63, w = t >> 6;
  const int lr = lane & 15, lg = lane >> 4;
  f32x4 acc0[2][4] = {}, acc1[2][4] = {};
#pragma unroll
  for (int ks = 0; ks < 4; ++ks) {
    us8 ah[2], al[2];
#pragma unroll
    for (int mt = 0; mt < 2; ++mt) {
      int ro = (lr + 16 * mt) * 136 + ks * 32 + lg * 8;
      ah[mt] = *(const us8*)&a_hi[ro];
      al[mt] = *(const us8*)&a_lo[ro];
    }
    us8 bh[4], bl[4];
#pragma unroll
    for (int cc = 0; cc < 4; ++cc) {
      long off = (long)((w * 4 + cc) * 16 + lr) * 128 + ks * 32 + lg * 8;
      bh[cc] = *(const us8*)&wkv_hi[off];
      bl[cc] = *(const us8*)&wkv_lo[off];
    }
#pragma unroll
    for (int mt = 0; mt < 2; ++mt)
#pragma unroll
      for (int cc = 0; cc < 4; ++cc) {
        acc0[mt][cc] = MFMA(asbf(ah[mt]), asbf(bh[cc]), acc0[mt][cc], 0, 0, 0);
        acc1[mt][cc] = MFMA(asbf(al[mt]), asbf(bh[cc]), acc1[mt][cc], 0, 0, 0);
        acc1[mt][cc] = MFMA(asbf(ah[mt]), asbf(bl[cc]), acc1[mt][cc], 0, 0, 0);
      }
  }
#pragma unroll
  for (int mt = 0; mt < 2; ++mt)
#pragma unroll
    for (int cc = 0; cc < 4; ++cc) {
      int c = (w * 4 + cc) * 16 + lr;
#pragma unroll
      for (int r = 0; r < 4; ++r)
        kvbuf[(lg * 4 + r + 16 * mt) * 264 + c] = acc0[mt][cc][r] + acc1[mt][cc][r];
    }
  __syncthreads();
#pragma unroll
  for (int jo = 0; jo < 4; ++jo) {
    int c = jo * 64 + (t & 63);
    int i4 = t >> 6;
    int kcol = (c < 128) ? c : (c - 128);
    us8 h8, l8;
#pragma unroll
    for (int jq = 0; jq < 8; ++jq) {
      int n = i4 * 8 + jq;
      float kv = kvbuf[n * 264 + kcol];
      float ek = __expf(kv);
      float val = (c < 128) ? ek * kvbuf[n * 264 + c + 128] : ek;
      u16 h, l;
      bsplit(val, h, l);
      h8[jq] = h;
      l8[jq] = l;
    }
    long o = (((long)b * 128 + (n0 >> 3) + i4) * 256 + c) * 8;
    *(us8*)&ekkP_hi[o] = h8;
    *(us8*)&ekkP_lo[o] = l8;
  }
  {
    int pl = t >> 7, r = t & 127;
    int dgrp = r >> 3, nb = r & 7;
    const u16* src = pl ? a_lo : a_hi;
    u16* dst = pl ? nodesP_lo : nodesP_hi;
#pragma unroll
    for (int i = 0; i < 4; ++i) {
      int n = nb + 8 * i;
      us8 v = *(const us8*)&src[n * 136 + dgrp * 8];
      *(us8*)&dst[(((long)(b * 16 + dgrp)) * 1024 + n0 + n) * 8] = v;
    }
  }
}

// ---------------- K2: q GEMM + sigmoid -> qsig f32 [32K][128] ----------------
__global__ __launch_bounds__(256) void qsig_prep(
    const float* __restrict__ q1m, const float* __restrict__ q2m,
    const float* __restrict__ lnm, const float* __restrict__ loadv,
    const float* __restrict__ leftv, const float* __restrict__ Wql,
    const u16* __restrict__ wcat_hi, const u16* __restrict__ wcat_lo,
    float* __restrict__ qsig) {
  const int t = threadIdx.x;
  const int lane = t & 63, w = t >> 6;
  const int lr = lane & 15, lg = lane >> 4;
  const long p0 = (long)blockIdx.x * 16;
  const long arow = p0 + lr;
  f32x4 qacc[2] = {};
#pragma unroll 2
  for (int s = 0; s < 12; ++s) {
    const float* __restrict__ src = (s < 4) ? q1m : (s < 8) ? q2m : lnm;
    long ao = arow * 128 + (s & 3) * 32 + lg * 8;
    float4 a0 = *(const float4*)&src[ao];
    float4 a1 = *(const float4*)&src[ao + 4];
    float av[8] = {a0.x, a0.y, a0.z, a0.w, a1.x, a1.y, a1.z, a1.w};
    us8 ah, al;
#pragma unroll
    for (int jq = 0; jq < 8; ++jq) {
      u16 hh, ll;
      tsplit(av[jq], hh, ll);
      ah[jq] = hh;
      al[jq] = ll;
    }
#pragma unroll
    for (int cf = 0; cf < 2; ++cf) {
      int c = w * 32 + cf * 16 + lr;
      us8 bh = *(const us8*)&wcat_hi[c * 384 + s * 32 + lg * 8];
      us8 bl = *(const us8*)&wcat_lo[c * 384 + s * 32 + lg * 8];
      qacc[cf] = MFMA(asbf(ah), asbf(bh), qacc[cf], 0, 0, 0);
      qacc[cf] = MFMA(asbf(al), asbf(bh), qacc[cf], 0, 0, 0);
      qacc[cf] = MFMA(asbf(ah), asbf(bl), qacc[cf], 0, 0, 0);
    }
  }
#pragma unroll
  for (int cf = 0; cf < 2; ++cf) {
    int c = w * 32 + cf * 16 + lr;
    float wl1 = Wql[128 * 128 + c], wl2 = Wql[129 * 128 + c];
#pragma unroll
    for (int r = 0; r < 4; ++r) {
      int row = lg * 4 + r;
      float qv = qacc[cf][r] + loadv[p0 + row] * wl1 + leftv[p0 + row] * wl2;
      qsig[(p0 + row) * 128 + c] = 1.0f / (1.0f + __expf(-qv));
    }
  }
}

// df ring element (held by reference -> static indexing, no scratch)
struct DFset {
  float4 d0, d1, f0, f1;
};

// ---------------- K3: FUSED bias + [num|den] GEMM + AFT + score + softmax ----------------
// 512 blocks (2/CU) x 256 thr (4 waves), 64-row tiles.
// Phase A (R13 structure at 64 rows): A dbuf LDS, B from regs, df 2-deep ring,
//   num/den lane-paired -> AFT written split-bf16 to LDS; bias16 -> d_out (L2-hot).
// Phase B (R10 score): per 16-row subtile, transposed score GEMM from aft LDS +
//   nodesP, bias16 read back (same block, L2), softmax, float4 out stores.
__global__ __launch_bounds__(256, 2) void fused_ndscore(
    const float* __restrict__ cdist, const float* __restrict__ ninf,
    const u16* __restrict__ ekkP_hi, const u16* __restrict__ ekkP_lo,
    const float* __restrict__ qsig, const u16* __restrict__ nodesP_hi,
    const u16* __restrict__ nodesP_lo, u16* bias16, float* out,
    const float* __restrict__ logs, const float* __restrict__ aal,
    const float* __restrict__ pal) {
  __shared__ u16 Adb[2][4352];   // [buf][ptile4][pl2][oct4][136]
  __shared__ u16 aft_hi[64 * 136];
  __shared__ u16 aft_lo[64 * 136];
  __shared__ float psum[16 * 4];
  __shared__ float invb[16];

  const int t = threadIdx.x;
  const int lane = t & 63, w = t >> 6;
  const int lr = lane & 15, lg = lane >> 4;
  const int xcd = blockIdx.x & 7, j = blockIdx.x >> 3;  // j 0..63
  const int b = xcd * 4 + (j & 3);
  const int pt = j >> 2;  // 0..15 (64 rows)
  const long bp = (long)b * Pp + pt * 64;
  const float c1 = logs[0] * aal[0];
  const float c2 = logs[0] * pal[0];
  const long bsrc = (long)b * 128 * 2048;

  // ===== Phase A: [num|den] = e_bias @ ekk =====
  const int srow = t >> 2, soct = t & 3;  // 64 rows x 4 octs
  const long arow = bp + srow;
  const long tbase = (arow >> 4) * 32768;
  const int spr = srow & 15, sptile = srow >> 4;
  const int wrr = w >> 1, wcc = w & 1;  // wave: rows wrr*32..+32; cols wcc*64(num)/+128(den)

  int ccol[8];
#pragma unroll
  for (int ct = 0; ct < 8; ++ct)
    ccol[ct] = ((ct < 4) ? (wcc * 64 + ct * 16) : (128 + wcc * 64 + (ct - 4) * 16)) + lr;

  DFset dfA, dfB;
  us8 ebh, ebl;

  auto load_df = [&](DFset& df, int s) {
    long ao = arow * 1024 + s * 32 + soct * 8;
    df.d0 = *(const float4*)&cdist[ao];
    df.d1 = *(const float4*)&cdist[ao + 4];
    df.f0 = *(const float4*)&ninf[ao];
    df.f1 = *(const float4*)&ninf[ao + 4];
  };
  auto compute_eb = [&](DFset& df, int s) {
    float dv[8] = {df.d0.x, df.d0.y, df.d0.z, df.d0.w, df.d1.x, df.d1.y, df.d1.z, df.d1.w};
    float nv[8] = {df.f0.x, df.f0.y, df.f0.z, df.f0.w, df.f1.x, df.f1.y, df.f1.z, df.f1.w};
    us8 q8;
#pragma unroll
    for (int jq = 0; jq < 8; ++jq) {
      float e = __expf(fmaf(-c1, dv[jq], nv[jq]));
      u16 h, l;
      tsplit(e, h, l);
      ebh[jq] = h;
      ebl[jq] = l;
      float x = fminf(fmaxf(c2 * dv[jq], 0.f), 15.999f);
      q8[jq] = (nv[jq] < -1e5f) ? (u16)0xFFFF : (u16)(x * 4096.f + 0.5f);
    }
    *(us8*)&bias16[tbase + ((s * 4 + soct) * 16 + spr) * 8] = q8;
  };
  auto write_A = [&](int buf) {
    *(us8*)&Adb[buf][((sptile * 2 + 0) * 4 + soct) * 136 + spr * 8] = ebh;
    *(us8*)&Adb[buf][((sptile * 2 + 1) * 4 + soct) * 136 + spr * 8] = ebl;
  };

  f32x4 acc[2][8] = {};  // [mt][ct]

  load_df(dfA, 0);
  load_df(dfB, 1);
  compute_eb(dfA, 0);
  write_A(0);
  asm volatile("s_waitcnt lgkmcnt(0)" ::: "memory");
  __builtin_amdgcn_s_barrier();
  __builtin_amdgcn_sched_barrier(0);

  auto stage = [&](int s, DFset& refill, DFset& consume) {
    us8 Bh[8], Bl[8];
    {
      long sb = bsrc + (long)s * 8192 + (long)lg * 2048;
#pragma unroll
      for (int ct = 0; ct < 8; ++ct) {
        Bh[ct] = *(const us8*)&ekkP_hi[sb + ccol[ct] * 8];
        Bl[ct] = *(const us8*)&ekkP_lo[sb + ccol[ct] * 8];
      }
    }
    if (s < 30) load_df(refill, s + 2);
    if (s < 31) {
      compute_eb(consume, s + 1);
      write_A((s + 1) & 1);
    }
    const int buf = s & 1;
    us8 ah[2], al[2];
#pragma unroll
    for (int mt = 0; mt < 2; ++mt) {
      int ptl = wrr * 2 + mt;
      ah[mt] = *(const us8*)&Adb[buf][((ptl * 2 + 0) * 4 + lg) * 136 + lr * 8];
      al[mt] = *(const us8*)&Adb[buf][((ptl * 2 + 1) * 4 + lg) * 136 + lr * 8];
    }
#pragma unroll
    for (int ct = 0; ct < 8; ++ct) {
#pragma unroll
      for (int mt = 0; mt < 2; ++mt) {
        acc[mt][ct] = MFMA(asbf(ah[mt]), asbf(Bh[ct]), acc[mt][ct], 0, 0, 0);
        acc[mt][ct] = MFMA(asbf(al[mt]), asbf(Bh[ct]), acc[mt][ct], 0, 0, 0);
        acc[mt][ct] = MFMA(asbf(ah[mt]), asbf(Bl[ct]), acc[mt][ct], 0, 0, 0);
      }
    }
    asm volatile("s_waitcnt lgkmcnt(0)" ::: "memory");
    __builtin_amdgcn_s_barrier();
    __builtin_amdgcn_sched_barrier(0);
  };

#pragma unroll 1
  for (int s2 = 0; s2 < 32; s2 += 2) {
    stage(s2, dfA, dfB);
    stage(s2 + 1, dfB, dfA);
  }

  // AFT epilogue: lane-local num/den -> split-bf16 into aft LDS
#pragma unroll
  for (int mt = 0; mt < 2; ++mt)
#pragma unroll
    for (int ct = 0; ct < 4; ++ct) {
      int cn = wcc * 64 + ct * 16 + lr;
#pragma unroll
      for (int r = 0; r < 4; ++r) {
        int row = wrr * 32 + mt * 16 + lg * 4 + r;
        float sig = qsig[(bp + row) * 128 + cn];
        float aftv = sig * acc[mt][ct][r] * __builtin_amdgcn_rcpf(acc[mt][ct + 4][r] + 1e-20f);
        u16 h, l;
        bsplit(aftv, h, l);
        aft_hi[row * 136 + cn] = h;
        aft_lo[row * 136 + cn] = l;
      }
    }
  __threadfence();  // bias16 (global) visible past L1 for phase B reads
  __syncthreads();

  // ===== Phase B: score GEMM (transposed) + tanh-clip softmax, 4 subtiles =====
#pragma unroll 1
  for (int st = 0; st < 4; ++st) {
    const int tile = (int)(bp >> 4) + st;
    f32x4 sacc[16];
#pragma unroll
    for (int cf = 0; cf < 16; ++cf) sacc[cf] = (f32x4){0.f, 0.f, 0.f, 0.f};
#pragma unroll
    for (int ks = 0; ks < 4; ++ks) {
      us8 ah = *(const us8*)&aft_hi[(st * 16 + lr) * 136 + (ks * 4 + lg) * 8];
      us8 al = *(const us8*)&aft_lo[(st * 16 + lr) * 136 + (ks * 4 + lg) * 8];
      long nb = ((long)(b * 16 + ks * 4 + lg)) * 1024;
      auto bld = [&](int cf, us8& bh, us8& bl) {
        long o = (nb + w * 256 + cf * 16 + lr) * 8;
        bh = *(const us8*)&nodesP_hi[o];
        bl = *(const us8*)&nodesP_lo[o];
      };
      us8 bh0, bl0, bh1, bl1;
      bld(0, bh0, bl0);
      bld(1, bh1, bl1);
#pragma unroll
      for (int cf = 0; cf < 16; ++cf) {
        us8 nh = bh1, nl = bl1;
        if (cf < 14) bld(cf + 2, nh, nl);
        sacc[cf] = MFMA(asbf(bh0), asbf(ah), sacc[cf], 0, 0, 0);
        sacc[cf] = MFMA(asbf(bl0), asbf(ah), sacc[cf], 0, 0, 0);
        sacc[cf] = MFMA(asbf(bh0), asbf(al), sacc[cf], 0, 0, 0);
        bh0 = bh1; bl0 = bl1; bh1 = nh; bl1 = nl;
      }
    }

    const long btile = (long)tile * 32768;
    float rs = 0.f;
#pragma unroll
    for (int cf = 0; cf < 16; ++cf) {
      int nc = w * 32 + cf * 2 + (lg >> 1);
      int j0 = (lg & 1) * 4;
      us4 q4 = *(const us4*)&bias16[btile + (nc * 16 + lr) * 8 + j0];
#pragma unroll
      for (int r = 0; r < 4; ++r) {
        u16 qv = q4[r];
        float sv = fmaf(sacc[cf][r], INV_SQRT_E, (float)qv * -2.44140625e-4f);
        float e = exp10tanh(sv);
        e = (qv == (u16)0xFFFF) ? 0.f : e;
        sacc[cf][r] = e;
        rs += e;
      }
    }
    rs += __shfl_xor(rs, 16);
    rs += __shfl_xor(rs, 32);
    if (lane < 16) psum[lr * 4 + w] = rs;
    __syncthreads();
    if (t < 16)
      invb[t] = 1.0f / (psum[t * 4] + psum[t * 4 + 1] + psum[t * 4 + 2] + psum[t * 4 + 3]);
    __syncthreads();

    const float inv = invb[lr];
    const long ro = (bp + st * 16 + lr) * (long)Nn + w * 256;
#pragma unroll
    for (int cf = 0; cf < 16; ++cf) {
      float4 v;
      v.x = sacc[cf][0] * inv;
      v.y = sacc[cf][1] * inv;
      v.z = sacc[cf][2] * inv;
      v.w = sacc[cf][3] * inv;
      *(float4*)&out[ro + cf * 16 + lg * 4] = v;
    }
    __syncthreads();
  }
}

extern "C" void kernel_launch(void* const* d_in, const int* in_sizes, int n_in,
                              void* d_out, int out_size, void* d_ws, size_t ws_size,
                              hipStream_t stream) {
  const float* nodes = (const float*)d_in[0];
  const float* q1m = (const float*)d_in[1];
  const float* q2m = (const float*)d_in[2];
  const float* lnm = (const float*)d_in[3];
  const float* loadv = (const float*)d_in[4];
  const float* leftv = (const float*)d_in[5];
  const float* cdist = (const float*)d_in[6];
  const float* logs = (const float*)d_in[7];
  const float* ninf = (const float*)d_in[8];
  const float* Wq1 = (const float*)d_in[9];
  const float* Wq2 = (const float*)d_in[10];
  const float* Wql = (const float*)d_in[11];
  const float* Wk = (const float*)d_in[12];
  const float* Wv = (const float*)d_in[13];
  const float* aalpha = (const float*)d_in[14];
  const float* palpha = (const float*)d_in[15];

  char* ws = (char*)d_ws;
  u16* ekkP_hi = (u16*)ws;                      // 16 MB
  u16* ekkP_lo = (u16*)(ws + (16ul << 20));     // 16 MB
  u16* nodesP_hi = (u16*)(ws + (32ul << 20));   // 8 MB
  u16* nodesP_lo = (u16*)(ws + (40ul << 20));   // 8 MB
  float* qsig = (float*)(ws + (48ul << 20));    // 16 MB
  u16* wcat_hi = (u16*)(ws + (64ul << 20));
  u16* wcat_lo = wcat_hi + 128 * 384;
  u16* wkv_hi = wcat_lo + 128 * 384;
  u16* wkv_lo = wkv_hi + 256 * 128;
  u16* bias16 = (u16*)d_out;  // first 32KB of each 64KB out-tile; same-block L2 handoff

  prep_weights<<<2, 256, 0, stream>>>(Wq1, Wq2, Wql, Wk, Wv, wcat_hi, wcat_lo, wkv_hi, wkv_lo);
  kv_prep<<<Bb * Nn / 32, 256, 0, stream>>>(nodes, wkv_hi, wkv_lo, ekkP_hi, ekkP_lo,
                                            nodesP_hi, nodesP_lo);
  qsig_prep<<<2048, 256, 0, stream>>>(q1m, q2m, lnm, loadv, leftv, Wql, wcat_hi, wcat_lo,
                                      qsig);
  fused_ndscore<<<512, 256, 0, stream>>>(cdist, ninf, ekkP_hi, ekkP_lo, qsig,
                                         nodesP_hi, nodesP_lo, bias16, (float*)d_out,
                                         logs, aalpha, palpha);
}

// Round 19
// 340.648 us; speedup vs baseline: 1.7784x; 1.7784x over previous
//
#include <hip/hip_runtime.h>
#include <math.h>

#define Bb 32
#define Pp 1024
#define Nn 1024

typedef unsigned short u16;
typedef __bf16 bf16x8 __attribute__((ext_vector_type(8)));
typedef float f32x4 __attribute__((ext_vector_type(4)));
typedef u16 us8 __attribute__((ext_vector_type(8)));
typedef u16 us4 __attribute__((ext_vector_type(4)));

#define MFMA __builtin_amdgcn_mfma_f32_16x16x32_bf16

static constexpr float INV_SQRT_E = 0.08838834764831845f;  // 1/sqrt(128)

__device__ __forceinline__ bf16x8 asbf(us8 v) { return __builtin_bit_cast(bf16x8, v); }

// RTN split: x ~= hi + lo to ~2^-17 rel
__device__ __forceinline__ void bsplit(float x, u16& h, u16& l) {
  unsigned u = __float_as_uint(x);
  unsigned r = u + 0x7FFF + ((u >> 16) & 1);
  h = (u16)(r >> 16);
  float hf = __uint_as_float((unsigned)h << 16);
  float lof = x - hf;
  unsigned u2 = __float_as_uint(lof);
  unsigned r2 = u2 + 0x7FFF + ((u2 >> 16) & 1);
  l = (u16)(r2 >> 16);
}

// trunc split: x ~= hi + lo to ~2^-16 rel, cheap
__device__ __forceinline__ void tsplit(float x, u16& h, u16& l) {
  unsigned u = __float_as_uint(x);
  h = (u16)(u >> 16);
  float lof = x - __uint_as_float(u & 0xFFFF0000u);
  l = (u16)(__float_as_uint(lof) >> 16);
}

// exp(10*tanh(s)) with rcp instead of full divide (~1e-7 rel err)
__device__ __forceinline__ float exp10tanh(float s) {
  float ax = fabsf(s);
  float u = __expf(-2.0f * ax);                    // (0,1]
  float r = __builtin_amdgcn_rcpf(1.0f + u);
  float tt = fmaf(-2.0f * u, r, 1.0f);             // tanh(ax)
  tt = copysignf(tt, s);
  return __expf(10.0f * tt);
}

// ---------------- K0: transposed split weight planes ----------------
__global__ __launch_bounds__(256) void prep_weights(
    const float* __restrict__ Wq1, const float* __restrict__ Wq2,
    const float* __restrict__ Wql, const float* __restrict__ Wk,
    const float* __restrict__ Wv, u16* __restrict__ wcat_hi, u16* __restrict__ wcat_lo,
    u16* __restrict__ wkv_hi, u16* __restrict__ wkv_lo) {
  int t = threadIdx.x;
  if (blockIdx.x == 0) {
    for (int i = t; i < 128 * 384; i += 256) {
      int c = i / 384, k = i % 384;
      float v = (k < 128) ? Wq1[k * 128 + c]
                          : (k < 256) ? Wq2[(k - 128) * 128 + c] : Wql[(k - 256) * 128 + c];
      u16 h, l;
      bsplit(v, h, l);
      wcat_hi[i] = h;
      wcat_lo[i] = l;
    }
  } else {
    for (int i = t; i < 256 * 128; i += 256) {
      int c = i >> 7, k = i & 127;
      float v = (c < 128) ? Wk[k * 128 + c] : Wv[k * 128 + (c - 128)];
      u16 h, l;
      bsplit(v, h, l);
      wkv_hi[i] = h;
      wkv_lo[i] = l;
    }
  }
}

// ---------------- K1: k/v GEMM -> ekkP ([b][nch128][c256][8]) + nodesP ----------------
__global__ __launch_bounds__(256, 1) void kv_prep(
    const float* __restrict__ nodes, const u16* __restrict__ wkv_hi,
    const u16* __restrict__ wkv_lo, u16* __restrict__ ekkP_hi, u16* __restrict__ ekkP_lo,
    u16* __restrict__ nodesP_hi, u16* __restrict__ nodesP_lo) {
  __shared__ u16 a_hi[32 * 136], a_lo[32 * 136];
  __shared__ float kvbuf[32 * 264];
  const int t = threadIdx.x;
  const int xcd = blockIdx.x & 7, jj = blockIdx.x >> 3;
  const int b = xcd * 4 + (jj >> 5);
  const int n0 = (jj & 31) * 32;
  for (int i = t; i < 4096; i += 256) {
    int n = i >> 7, d = i & 127;
    float v = nodes[((long)(b * 1024 + n0 + n)) * 128 + d];
    u16 h, l;
    bsplit(v, h, l);
    a_hi[n * 136 + d] = h;
    a_lo[n * 136 + d] = l;
  }
  __syncthreads();
  const int lane = t & 63, w = t >> 6;
  const int lr = lane & 15, lg = lane >> 4;
  f32x4 acc0[2][4] = {}, acc1[2][4] = {};
#pragma unroll
  for (int ks = 0; ks < 4; ++ks) {
    us8 ah[2], al[2];
#pragma unroll
    for (int mt = 0; mt < 2; ++mt) {
      int ro = (lr + 16 * mt) * 136 + ks * 32 + lg * 8;
      ah[mt] = *(const us8*)&a_hi[ro];
      al[mt] = *(const us8*)&a_lo[ro];
    }
    us8 bh[4], bl[4];
#pragma unroll
    for (int cc = 0; cc < 4; ++cc) {
      long off = (long)((w * 4 + cc) * 16 + lr) * 128 + ks * 32 + lg * 8;
      bh[cc] = *(const us8*)&wkv_hi[off];
      bl[cc] = *(const us8*)&wkv_lo[off];
    }
#pragma unroll
    for (int mt = 0; mt < 2; ++mt)
#pragma unroll
      for (int cc = 0; cc < 4; ++cc) {
        acc0[mt][cc] = MFMA(asbf(ah[mt]), asbf(bh[cc]), acc0[mt][cc], 0, 0, 0);
        acc1[mt][cc] = MFMA(asbf(al[mt]), asbf(bh[cc]), acc1[mt][cc], 0, 0, 0);
        acc1[mt][cc] = MFMA(asbf(ah[mt]), asbf(bl[cc]), acc1[mt][cc], 0, 0, 0);
      }
  }
#pragma unroll
  for (int mt = 0; mt < 2; ++mt)
#pragma unroll
    for (int cc = 0; cc < 4; ++cc) {
      int c = (w * 4 + cc) * 16 + lr;
#pragma unroll
      for (int r = 0; r < 4; ++r)
        kvbuf[(lg * 4 + r + 16 * mt) * 264 + c] = acc0[mt][cc][r] + acc1[mt][cc][r];
    }
  __syncthreads();
#pragma unroll
  for (int jo = 0; jo < 4; ++jo) {
    int c = jo * 64 + (t & 63);
    int i4 = t >> 6;
    int kcol = (c < 128) ? c : (c - 128);
    us8 h8, l8;
#pragma unroll
    for (int jq = 0; jq < 8; ++jq) {
      int n = i4 * 8 + jq;
      float kv = kvbuf[n * 264 + kcol];
      float ek = __expf(kv);
      float val = (c < 128) ? ek * kvbuf[n * 264 + c + 128] : ek;
      u16 h, l;
      bsplit(val, h, l);
      h8[jq] = h;
      l8[jq] = l;
    }
    long o = (((long)b * 128 + (n0 >> 3) + i4) * 256 + c) * 8;
    *(us8*)&ekkP_hi[o] = h8;
    *(us8*)&ekkP_lo[o] = l8;
  }
  {
    int pl = t >> 7, r = t & 127;
    int dgrp = r >> 3, nb = r & 7;
    const u16* src = pl ? a_lo : a_hi;
    u16* dst = pl ? nodesP_lo : nodesP_hi;
#pragma unroll
    for (int i = 0; i < 4; ++i) {
      int n = nb + 8 * i;
      us8 v = *(const us8*)&src[n * 136 + dgrp * 8];
      *(us8*)&dst[(((long)(b * 16 + dgrp)) * 1024 + n0 + n) * 8] = v;
    }
  }
}

// ---------------- K2: q GEMM + sigmoid -> qsig f32 [32K][128] ----------------
__global__ __launch_bounds__(256) void qsig_prep(
    const float* __restrict__ q1m, const float* __restrict__ q2m,
    const float* __restrict__ lnm, const float* __restrict__ loadv,
    const float* __restrict__ leftv, const float* __restrict__ Wql,
    const u16* __restrict__ wcat_hi, const u16* __restrict__ wcat_lo,
    float* __restrict__ qsig) {
  const int t = threadIdx.x;
  const int lane = t & 63, w = t >> 6;
  const int lr = lane & 15, lg = lane >> 4;
  const long p0 = (long)blockIdx.x * 16;
  const long arow = p0 + lr;
  f32x4 qacc[2] = {};
#pragma unroll 2
  for (int s = 0; s < 12; ++s) {
    const float* __restrict__ src = (s < 4) ? q1m : (s < 8) ? q2m : lnm;
    long ao = arow * 128 + (s & 3) * 32 + lg * 8;
    float4 a0 = *(const float4*)&src[ao];
    float4 a1 = *(const float4*)&src[ao + 4];
    float av[8] = {a0.x, a0.y, a0.z, a0.w, a1.x, a1.y, a1.z, a1.w};
    us8 ah, al;
#pragma unroll
    for (int jq = 0; jq < 8; ++jq) {
      u16 hh, ll;
      tsplit(av[jq], hh, ll);
      ah[jq] = hh;
      al[jq] = ll;
    }
#pragma unroll
    for (int cf = 0; cf < 2; ++cf) {
      int c = w * 32 + cf * 16 + lr;
      us8 bh = *(const us8*)&wcat_hi[c * 384 + s * 32 + lg * 8];
      us8 bl = *(const us8*)&wcat_lo[c * 384 + s * 32 + lg * 8];
      qacc[cf] = MFMA(asbf(ah), asbf(bh), qacc[cf], 0, 0, 0);
      qacc[cf] = MFMA(asbf(al), asbf(bh), qacc[cf], 0, 0, 0);
      qacc[cf] = MFMA(asbf(ah), asbf(bl), qacc[cf], 0, 0, 0);
    }
  }
#pragma unroll
  for (int cf = 0; cf < 2; ++cf) {
    int c = w * 32 + cf * 16 + lr;
    float wl1 = Wql[128 * 128 + c], wl2 = Wql[129 * 128 + c];
#pragma unroll
    for (int r = 0; r < 4; ++r) {
      int row = lg * 4 + r;
      float qv = qacc[cf][r] + loadv[p0 + row] * wl1 + leftv[p0 + row] * wl2;
      qsig[(p0 + row) * 128 + c] = 1.0f / (1.0f + __expf(-qv));
    }
  }
}

// df ring element (held by reference -> static indexing, no scratch)
struct DFset {
  float4 d0, d1, f0, f1;
};

// ---------------- K3: fused bias + [num|den] GEMM (128r x 256c x K1024) + AFT epilogue ----------------
// 256 blocks (1/CU), 512 thr / 8 waves. lgkm-only barriers keep global loads in
// flight across stages; cdist/ninf prefetched 2 stages deep (DFset ring of 2).
__global__ __launch_bounds__(512, 2) void ndaft_gemm(
    const float* __restrict__ cdist, const float* __restrict__ ninf,
    const u16* __restrict__ ekkP_hi, const u16* __restrict__ ekkP_lo,
    const float* __restrict__ qsig, u16* __restrict__ aftP_hi,
    u16* __restrict__ aftP_lo, u16* __restrict__ bias16,
    const float* __restrict__ logs, const float* __restrict__ aal,
    const float* __restrict__ pal) {
  // A: [ptile8][pl2][oct4][136] u16 = 8704 ; B at 8704: hi[oct4][c256][8]=8192, lo +8192
  __shared__ u16 lds[25088];  // 50176 B
  const int t = threadIdx.x;
  const int lane = t & 63, w = t >> 6;
  const int lr = lane & 15, lg = lane >> 4;
  const int wr = w >> 2, wc = w & 3;
  const int xcd = blockIdx.x & 7, j = blockIdx.x >> 3;  // j 0..31
  const int b = xcd * 4 + (j & 3);
  const int pt = j >> 2;  // 0..7 (128 rows each)
  const long bp = (long)b * Pp + pt * 128;
  const float c1 = logs[0] * aal[0];
  const float c2 = logs[0] * pal[0];

  const int srow = t >> 2, soct = t & 3;  // A staging: 128 rows x 4 K-octs
  const long arow = bp + srow;
  const long tbase = (arow >> 4) * 32768;
  const int spr = srow & 15, sptile = srow >> 4;
  const long bsrc = (long)b * 128 * 2048;

  DFset dfA, dfB;
  us8 bst[4];
  us8 ebh, ebl;

  auto load_df = [&](DFset& df, int s) {
    long ao = arow * 1024 + s * 32 + soct * 8;
    df.d0 = *(const float4*)&cdist[ao];
    df.d1 = *(const float4*)&cdist[ao + 4];
    df.f0 = *(const float4*)&ninf[ao];
    df.f1 = *(const float4*)&ninf[ao + 4];
  };
  auto load_bst = [&](int s) {
    long sb = bsrc + (long)s * 8192;
#pragma unroll
    for (int i = 0; i < 2; ++i) {
      bst[i] = *(const us8*)&ekkP_hi[sb + (i * 512 + t) * 8];
      bst[i + 2] = *(const us8*)&ekkP_lo[sb + (i * 512 + t) * 8];
    }
  };
  auto compute_eb = [&](DFset& df, int s) {
    float dv[8] = {df.d0.x, df.d0.y, df.d0.z, df.d0.w, df.d1.x, df.d1.y, df.d1.z, df.d1.w};
    float nv[8] = {df.f0.x, df.f0.y, df.f0.z, df.f0.w, df.f1.x, df.f1.y, df.f1.z, df.f1.w};
    us8 q8;
#pragma unroll
    for (int jq = 0; jq < 8; ++jq) {
      float e = __expf(fmaf(-c1, dv[jq], nv[jq]));
      u16 h, l;
      tsplit(e, h, l);
      ebh[jq] = h;
      ebl[jq] = l;
      float x = fminf(fmaxf(c2 * dv[jq], 0.f), 15.999f);
      q8[jq] = (nv[jq] < -1e5f) ? (u16)0xFFFF : (u16)(x * 4096.f + 0.5f);
    }
    *(us8*)&bias16[tbase + ((s * 4 + soct) * 16 + spr) * 8] = q8;
  };
  auto write_lds = [&]() {
    *(us8*)&lds[((sptile * 2 + 0) * 4 + soct) * 136 + spr * 8] = ebh;
    *(us8*)&lds[((sptile * 2 + 1) * 4 + soct) * 136 + spr * 8] = ebl;
#pragma unroll
    for (int i = 0; i < 2; ++i) {
      *(us8*)&lds[8704 + (i * 512 + t) * 8] = bst[i];
      *(us8*)&lds[8704 + 8192 + (i * 512 + t) * 8] = bst[i + 2];
    }
  };

  f32x4 acc[4][4] = {};

  // prologue: df(0)->A, df(1)->B, bst(0); eb(0) from A
  load_df(dfA, 0);
  load_df(dfB, 1);
  load_bst(0);
  compute_eb(dfA, 0);

  // one stage; refill = df set to load s+2 into; consume = df set holding s+1
  auto stage = [&](int s, DFset& refill, DFset& consume) {
    // bar1: all waves' ds_reads of stage s-1 done (lgkm only; vmcnt stays in flight)
    asm volatile("s_waitcnt lgkmcnt(0)" ::: "memory");
    __builtin_amdgcn_s_barrier();
    __builtin_amdgcn_sched_barrier(0);
    write_lds();  // A(s) from eb regs, B(s) from bst (waits its vmcnt via dep)
    asm volatile("s_waitcnt lgkmcnt(0)" ::: "memory");
    __builtin_amdgcn_s_barrier();
    __builtin_amdgcn_sched_barrier(0);
    if (s < 31) load_bst(s + 1);          // global->reg, in flight over next barrier
    if (s < 30) load_df(refill, s + 2);   // HBM, 2 stages deep
    if (s < 31) compute_eb(consume, s + 1);
    us8 ah[4], al[4];
#pragma unroll
    for (int mt = 0; mt < 4; ++mt) {
      int ptl = wr * 4 + mt;
      ah[mt] = *(const us8*)&lds[((ptl * 2 + 0) * 4 + lg) * 136 + lr * 8];
      al[mt] = *(const us8*)&lds[((ptl * 2 + 1) * 4 + lg) * 136 + lr * 8];
    }
#pragma unroll
    for (int ct = 0; ct < 4; ++ct) {
      int c = (ct < 2) ? (wc * 32 + ct * 16 + lr) : (96 + wc * 32 + ct * 16 + lr);
      us8 bh = *(const us8*)&lds[8704 + lg * 2048 + c * 8];
      us8 bl = *(const us8*)&lds[8704 + 8192 + lg * 2048 + c * 8];
#pragma unroll
      for (int mt = 0; mt < 4; ++mt) {
        acc[mt][ct] = MFMA(asbf(ah[mt]), asbf(bh), acc[mt][ct], 0, 0, 0);
        acc[mt][ct] = MFMA(asbf(al[mt]), asbf(bh), acc[mt][ct], 0, 0, 0);
        acc[mt][ct] = MFMA(asbf(ah[mt]), asbf(bl), acc[mt][ct], 0, 0, 0);
      }
    }
  };

#pragma unroll 1
  for (int s2 = 0; s2 < 32; s2 += 2) {
    stage(s2, dfA, dfB);       // refill A with df(s2+2), consume B (df(s2+1))
    stage(s2 + 1, dfB, dfA);   // refill B with df(s2+3), consume A (df(s2+2))
  }

  // epilogue: aft = sig * num * rcp(den+eps) -> split bf16, packed aftP
#pragma unroll
  for (int mt = 0; mt < 4; ++mt)
#pragma unroll
    for (int ct = 0; ct < 2; ++ct) {
      int cn = wc * 32 + ct * 16 + lr;
      int nc = cn >> 3, jq = cn & 7;
#pragma unroll
      for (int r = 0; r < 4; ++r) {
        long gr = bp + wr * 64 + mt * 16 + lg * 4 + r;
        float sig = qsig[gr * 128 + cn];
        float aftv = sig * acc[mt][ct][r] * __builtin_amdgcn_rcpf(acc[mt][ct + 2][r] + 1e-20f);
        u16 h, l;
        bsplit(aftv, h, l);
        long idx = (gr >> 4) * 2048 + (nc * 16 + (gr & 15)) * 8 + jq;
        aftP_hi[idx] = h;
        aftP_lo[idx] = l;
      }
    }
}

// ---------------- K4: score GEMM (transposed) + tanh-clip softmax ----------------
__global__ __launch_bounds__(256, 4) void score_softmax(
    const u16* bias16, const u16* __restrict__ aftP_hi, const u16* __restrict__ aftP_lo,
    const u16* __restrict__ nodesP_hi, const u16* __restrict__ nodesP_lo,
    float* out) {
  __shared__ float psum[16 * 4];
  __shared__ float invb[16];
  const int t = threadIdx.x;
  const int lane = t & 63, w = t >> 6;  // w = n-quarter
  const int lr = lane & 15, lg = lane >> 4;
  const int xcd = blockIdx.x & 7, j = blockIdx.x >> 3;  // j 0..255
  const int b = xcd * 4 + (j >> 6);
  const int tl = j & 63;
  const int p0 = tl * 16;
  const long bp = (long)b * Pp + p0;
  const int tile = b * 64 + tl;

  f32x4 sacc[16] = {};
#pragma unroll
  for (int ks = 0; ks < 4; ++ks) {
    long aoff = (long)tile * 2048 + ((long)((ks * 4 + lg) * 16 + lr)) * 8;
    us8 ah = *(const us8*)&aftP_hi[aoff];
    us8 al = *(const us8*)&aftP_lo[aoff];
    long nb = ((long)(b * 16 + ks * 4 + lg)) * 1024;
    auto bld = [&](int cf, us8& bh, us8& bl) {
      long o = (nb + w * 256 + cf * 16 + lr) * 8;
      bh = *(const us8*)&nodesP_hi[o];
      bl = *(const us8*)&nodesP_lo[o];
    };
    us8 bh0, bl0, bh1, bl1;
    bld(0, bh0, bl0);
    bld(1, bh1, bl1);
#pragma unroll
    for (int cf = 0; cf < 16; ++cf) {
      us8 nh = bh1, nl = bl1;
      if (cf < 14) bld(cf + 2, nh, nl);  // issue 2 iterations ahead
      sacc[cf] = MFMA(asbf(bh0), asbf(ah), sacc[cf], 0, 0, 0);
      sacc[cf] = MFMA(asbf(bl0), asbf(ah), sacc[cf], 0, 0, 0);
      sacc[cf] = MFMA(asbf(bh0), asbf(al), sacc[cf], 0, 0, 0);
      bh0 = bh1; bl0 = bl1; bh1 = nh; bl1 = nl;
    }
  }

  const long btile = (long)tile * 32768;
  float rs = 0.f;
#pragma unroll
  for (int cf = 0; cf < 16; ++cf) {
    int nc = w * 32 + cf * 2 + (lg >> 1);
    int j0 = (lg & 1) * 4;
    us4 q4 = *(const us4*)&bias16[btile + (nc * 16 + lr) * 8 + j0];
#pragma unroll
    for (int r = 0; r < 4; ++r) {
      u16 qv = q4[r];
      float sv = fmaf(sacc[cf][r], INV_SQRT_E, (float)qv * -2.44140625e-4f);
      float e = exp10tanh(sv);
      e = (qv == (u16)0xFFFF) ? 0.f : e;
      sacc[cf][r] = e;
      rs += e;
    }
  }
  rs += __shfl_xor(rs, 16);
  rs += __shfl_xor(rs, 32);
  if (lane < 16) psum[lr * 4 + w] = rs;
  __syncthreads();
  if (t < 16)
    invb[t] = 1.0f / (psum[t * 4] + psum[t * 4 + 1] + psum[t * 4 + 2] + psum[t * 4 + 3]);
  __syncthreads();

  const float inv = invb[lr];
  const long ro = (bp + lr) * (long)Nn + w * 256;
#pragma unroll
  for (int cf = 0; cf < 16; ++cf) {
    float4 v;
    v.x = sacc[cf][0] * inv;
    v.y = sacc[cf][1] * inv;
    v.z = sacc[cf][2] * inv;
    v.w = sacc[cf][3] * inv;
    *(float4*)&out[ro + cf * 16 + lg * 4] = v;
  }
}

extern "C" void kernel_launch(void* const* d_in, const int* in_sizes, int n_in,
                              void* d_out, int out_size, void* d_ws, size_t ws_size,
                              hipStream_t stream) {
  const float* nodes = (const float*)d_in[0];
  const float* q1m = (const float*)d_in[1];
  const float* q2m = (const float*)d_in[2];
  const float* lnm = (const float*)d_in[3];
  const float* loadv = (const float*)d_in[4];
  const float* leftv = (const float*)d_in[5];
  const float* cdist = (const float*)d_in[6];
  const float* logs = (const float*)d_in[7];
  const float* ninf = (const float*)d_in[8];
  const float* Wq1 = (const float*)d_in[9];
  const float* Wq2 = (const float*)d_in[10];
  const float* Wql = (const float*)d_in[11];
  const float* Wk = (const float*)d_in[12];
  const float* Wv = (const float*)d_in[13];
  const float* aalpha = (const float*)d_in[14];
  const float* palpha = (const float*)d_in[15];

  char* ws = (char*)d_ws;
  u16* ekkP_hi = (u16*)ws;                      // 16 MB
  u16* ekkP_lo = (u16*)(ws + (16ul << 20));     // 16 MB
  u16* nodesP_hi = (u16*)(ws + (32ul << 20));   // 8 MB
  u16* nodesP_lo = (u16*)(ws + (40ul << 20));   // 8 MB
  float* qsig = (float*)(ws + (48ul << 20));    // 16 MB
  u16* aftP_hi = (u16*)(ws + (64ul << 20));     // 8 MB
  u16* aftP_lo = (u16*)(ws + (72ul << 20));     // 8 MB
  u16* wcat_hi = (u16*)(ws + (80ul << 20));
  u16* wcat_lo = wcat_hi + 128 * 384;
  u16* wkv_hi = wcat_lo + 128 * 384;
  u16* wkv_lo = wkv_hi + 256 * 128;
  u16* bias16 = (u16*)d_out;  // first 32KB of each 64KB out-tile; read-then-overwritten

  prep_weights<<<2, 256, 0, stream>>>(Wq1, Wq2, Wql, Wk, Wv, wcat_hi, wcat_lo, wkv_hi, wkv_lo);
  kv_prep<<<Bb * Nn / 32, 256, 0, stream>>>(nodes, wkv_hi, wkv_lo, ekkP_hi, ekkP_lo,
                                            nodesP_hi, nodesP_lo);
  qsig_prep<<<2048, 256, 0, stream>>>(q1m, q2m, lnm, loadv, leftv, Wql, wcat_hi, wcat_lo,
                                      qsig);
  ndaft_gemm<<<256, 512, 0, stream>>>(cdist, ninf, ekkP_hi, ekkP_lo, qsig, aftP_hi,
                                      aftP_lo, bias16, logs, aalpha, palpha);
  score_softmax<<<Bb * Pp / 16, 256, 0, stream>>>(
      bias16, aftP_hi, aftP_lo, nodesP_hi, nodesP_lo, (float*)d_out);
}